// Round 11
// baseline (78.935 us; speedup 1.0000x reference)
//
#include <hip/hip_runtime.h>
#include <math.h>

#define Bn 64
#define Rr 36
#define Ww 40
#define Dd 1024
#define GM 2304   // Bn*Rr
#define GN 2560   // Bn*Ww
#define NCONV 4864  // (GM*Dd + GN*Dd)/4/256
#define PAD 72      // att LDS pitch (u16)
#define SBP 64      // SSb/IIb global pitch (u16)
#define TSZ 1440    // G tile size in u16 (36*40)
#define EPSf 1e-8f

typedef unsigned short u16;
typedef __attribute__((ext_vector_type(8))) short bf16x8;
typedef __attribute__((ext_vector_type(4))) float f32x4;

struct alignas(8) U16x4 { u16 x, y, z, w; };

__device__ inline u16 f2bf(float x) {
    unsigned int u = __float_as_uint(x);
    u += 0x7FFFu + ((u >> 16) & 1u);
    return (u16)(u >> 16);
}
__device__ inline float bf2f(u16 h) {
    return __uint_as_float(((unsigned int)h) << 16);
}

__device__ __forceinline__ void gl_lds16(const u16* g, u16* l) {
    __builtin_amdgcn_global_load_lds(
        (const __attribute__((address_space(1))) void*)g,
        (__attribute__((address_space(3))) void*)l, 16, 0, 0);
}

// ================= prep: convert + grams (bf16-padded + fp32 diag) =================
__global__ __launch_bounds__(256) void prep_kernel(const float* __restrict__ im,
                                                   const float* __restrict__ s,
                                                   const int* __restrict__ s_l,
                                                   u16* __restrict__ Ab,
                                                   u16* __restrict__ Bb,
                                                   u16* __restrict__ SSb,
                                                   u16* __restrict__ IIb,
                                                   float* __restrict__ SSd,
                                                   float* __restrict__ IId) {
    __shared__ float red[3][64][37];
    int b = blockIdx.x, t = threadIdx.x;
    if (b < NCONV) {
        const int nA4 = GM * Dd / 4;
        int idx = b * 256 + t;
        if (idx < nA4) {
            float4 v = *(const float4*)(im + (size_t)idx * 4);
            U16x4 o = {f2bf(v.x), f2bf(v.y), f2bf(v.z), f2bf(v.w)};
            *(U16x4*)(Ab + (size_t)idx * 4) = o;
        } else {
            int i2 = idx - nA4;
            int f = i2 * 4;
            int row = f >> 10;
            int j = row / Ww, w = row - j * Ww;
            U16x4 o = {0, 0, 0, 0};
            if (w < s_l[j]) {
                float4 v = *(const float4*)(s + (size_t)f);
                o.x = f2bf(v.x); o.y = f2bf(v.y); o.z = f2bf(v.z); o.w = f2bf(v.w);
            }
            *(U16x4*)(Bb + (size_t)i2 * 4) = o;
        }
        return;
    }
    // ---- gram branch (128 blocks); rows clamped; garbage cells only land where
    // attention weights are exactly zero.
    int gb = b - NCONV;
    bool isS = gb < Bn;
    int idx = isS ? gb : gb - Bn;
    int n = isS ? Ww : Rr;
    const float* basef = isS ? (s + (size_t)idx * Ww * Dd) : (im + (size_t)idx * Rr * Dd);
    u16* outb = isS ? (SSb + (size_t)idx * 48 * SBP) : (IIb + (size_t)idx * 48 * SBP);
    float* outd = isS ? (SSd + (size_t)idx * Ww) : (IId + (size_t)idx * Rr);
    int lane = t & 63, wid = t >> 6;
    int frow = lane & 15, fk = (lane >> 4) * 8;

    f32x4 acc[3][3];
    for (int m = 0; m < 3; ++m)
        for (int p = 0; p < 3; ++p) acc[m][p] = (f32x4){0.f, 0.f, 0.f, 0.f};

    for (int ks = 0; ks < 8; ++ks) {
        int k0 = wid * 256 + ks * 32 + fk;
        bf16x8 f[3];
        for (int m = 0; m < 3; ++m) {
            int rr = m * 16 + frow;
            if (rr >= n) rr = n - 1;
            const float* p = basef + (size_t)rr * Dd + k0;
            float4 v0 = *(const float4*)p;
            float4 v1 = *(const float4*)(p + 4);
            bf16x8 fv;
            fv[0] = (short)f2bf(v0.x); fv[1] = (short)f2bf(v0.y);
            fv[2] = (short)f2bf(v0.z); fv[3] = (short)f2bf(v0.w);
            fv[4] = (short)f2bf(v1.x); fv[5] = (short)f2bf(v1.y);
            fv[6] = (short)f2bf(v1.z); fv[7] = (short)f2bf(v1.w);
            f[m] = fv;
        }
        for (int m = 0; m < 3; ++m)
            for (int p = 0; p < 3; ++p)
                acc[m][p] = __builtin_amdgcn_mfma_f32_16x16x32_bf16(f[m], f[p], acc[m][p], 0, 0, 0);
    }
    if (wid) {
        for (int m = 0; m < 3; ++m)
            for (int p = 0; p < 3; ++p)
                for (int q = 0; q < 4; ++q)
                    red[wid - 1][lane][(m * 3 + p) * 4 + q] = acc[m][p][q];
    }
    __syncthreads();
    if (wid == 0) {
        for (int wv = 0; wv < 3; ++wv)
            for (int m = 0; m < 3; ++m)
                for (int p = 0; p < 3; ++p)
                    for (int q = 0; q < 4; ++q)
                        acc[m][p][q] += red[wv][lane][(m * 3 + p) * 4 + q];
        int crow = (lane >> 4) * 4, ccol = lane & 15;
        for (int m = 0; m < 3; ++m)
            for (int p = 0; p < 3; ++p)
                for (int q = 0; q < 4; ++q) {
                    int row = m * 16 + crow + q;
                    int col = p * 16 + ccol;
                    float v = acc[m][p][q];
                    outb[row * SBP + col] = f2bf(v);
                    if (row == col && row < n) outd[row] = v;
                }
    }
}

// == MFMA bf16 GEMM: 64x128, BK=64, XOR swizzle, 3-buffer counted-vmcnt pipeline ==
__global__ __launch_bounds__(256) void gemm_mfma_kernel(const u16* __restrict__ Ab,
                                                        const u16* __restrict__ Bb,
                                                        u16* __restrict__ Gt) {
    __shared__ __align__(16) u16 As[3][64][64];    // 24 KB
    __shared__ __align__(16) u16 Bs[3][128][64];   // 48 KB
    int bn = blockIdx.x;
    int bm = blockIdx.y;
    int t = threadIdx.x;
    int lane = t & 63, wid = t >> 6;
    int wr = wid >> 1, wc = wid & 1;

    int lrow8 = lane >> 3;
    int sslot = (lane & 7) ^ lrow8;   // pre-swizzled global source, linear LDS dest
    const u16* ga = Ab + ((size_t)(bm * 64 + wid * 16) + lrow8) * Dd + sslot * 8;
    const u16* gb = Bb + ((size_t)(bn * 128 + wid * 32) + lrow8) * Dd + sslot * 8;

    f32x4 acc[2][4];
    for (int m = 0; m < 2; ++m)
        for (int n = 0; n < 4; ++n) acc[m][n] = (f32x4){0.f, 0.f, 0.f, 0.f};

    int frow = lane & 15;
    int cgr = lane >> 4;

#define STAGE(BI, KK) do { \
        gl_lds16(ga + (KK), &As[BI][wid * 16][0]); \
        gl_lds16(ga + (size_t)8 * Dd + (KK), &As[BI][wid * 16 + 8][0]); \
        gl_lds16(gb + (KK), &Bs[BI][wid * 32][0]); \
        gl_lds16(gb + (size_t)8 * Dd + (KK), &Bs[BI][wid * 32 + 8][0]); \
        gl_lds16(gb + (size_t)16 * Dd + (KK), &Bs[BI][wid * 32 + 16][0]); \
        gl_lds16(gb + (size_t)24 * Dd + (KK), &Bs[BI][wid * 32 + 24][0]); \
    } while (0)

    STAGE(0, 0);
    STAGE(1, 64);
#pragma unroll
    for (int s = 0; s < 16; ++s) {
        // counted vmcnt: keep next tile's 6 loads in flight across the barrier
        if (s < 15) asm volatile("s_waitcnt vmcnt(6)" ::: "memory");
        else        asm volatile("s_waitcnt vmcnt(0)" ::: "memory");
        __builtin_amdgcn_sched_barrier(0);
        __builtin_amdgcn_s_barrier();
        __builtin_amdgcn_sched_barrier(0);
        const int cur = s % 3;
        bf16x8 af[2][2], bf[4][2];
#pragma unroll
        for (int m = 0; m < 2; ++m) {
            int row = wr * 32 + m * 16 + frow;
#pragma unroll
            for (int ks = 0; ks < 2; ++ks) {
                int slot = (ks * 4 + cgr) ^ (row & 7);
                af[m][ks] = *(const bf16x8*)&As[cur][row][slot * 8];
            }
        }
#pragma unroll
        for (int n = 0; n < 4; ++n) {
            int row = wc * 64 + n * 16 + frow;
#pragma unroll
            for (int ks = 0; ks < 2; ++ks) {
                int slot = (ks * 4 + cgr) ^ (row & 7);
                bf[n][ks] = *(const bf16x8*)&Bs[cur][row][slot * 8];
            }
        }
        if (s + 2 < 16) STAGE((s + 2) % 3, (s + 2) * 64);
#pragma unroll
        for (int ks = 0; ks < 2; ++ks)
#pragma unroll
            for (int m = 0; m < 2; ++m)
#pragma unroll
                for (int n = 0; n < 4; ++n)
                    acc[m][n] = __builtin_amdgcn_mfma_f32_16x16x32_bf16(af[m][ks], bf[n][ks], acc[m][n], 0, 0, 0);
        // pin ds_reads before the next barrier (slot reuse safety, rule 18)
        asm volatile("s_waitcnt lgkmcnt(0)" ::: "memory");
        __builtin_amdgcn_sched_barrier(0);
    }
#undef STAGE

    // epilogue: scatter into pair-tile-major layout Gt[(i*64+j)][r][w]
    int crow0 = bm * 64 + wr * 32 + (lane >> 4) * 4;
    int ccol0 = bn * 128 + wc * 64 + (lane & 15);
    int tjv[4], wv[4];
#pragma unroll
    for (int n = 0; n < 4; ++n) {
        int col = ccol0 + n * 16;
        tjv[n] = col / 40;
        wv[n] = col - tjv[n] * 40;
    }
    for (int m = 0; m < 2; ++m)
        for (int q = 0; q < 4; ++q) {
            int row = crow0 + m * 16 + q;
            int ti = row / 36, r2 = row - ti * 36;
            u16* dstbase = Gt + (size_t)ti * Bn * TSZ + (size_t)r2 * 40;
            for (int n = 0; n < 4; ++n)
                dstbase[(size_t)tjv[n] * TSZ + wv[n]] = f2bf(acc[m][n][q]);
        }
}

// ---- quadratic form via MFMA: q[row] = e_row^T M e_row ----
__device__ __forceinline__ void quad_mfma(const u16* att, const u16* M,
                                          float* qout, int nq, int lane) {
    int c = lane & 15, g4 = lane >> 4;
    f32x4 acc[3][3];
#pragma unroll
    for (int m = 0; m < 3; ++m)
#pragma unroll
        for (int p = 0; p < 3; ++p) acc[m][p] = (f32x4){0.f, 0.f, 0.f, 0.f};
#pragma unroll
    for (int ks = 0; ks < 2; ++ks) {
        bf16x8 fa[3], fb[3];
#pragma unroll
        for (int m = 0; m < 3; ++m)
            fa[m] = *(const bf16x8*)&att[(m * 16 + c) * PAD + g4 * 8 + ks * 32];
#pragma unroll
        for (int p = 0; p < 3; ++p)
            fb[p] = *(const bf16x8*)(M + (size_t)(p * 16 + c) * SBP + g4 * 8 + ks * 32);
#pragma unroll
        for (int m = 0; m < 3; ++m)
#pragma unroll
            for (int p = 0; p < 3; ++p)
                acc[m][p] = __builtin_amdgcn_mfma_f32_16x16x32_bf16(fa[m], fb[p], acc[m][p], 0, 0, 0);
    }
#pragma unroll
    for (int m = 0; m < 3; ++m)
#pragma unroll
        for (int q = 0; q < 4; ++q) {
            int row = m * 16 + g4 * 4 + q;
            float sp = 0.f;
#pragma unroll
            for (int p = 0; p < 3; ++p)
                sp += acc[m][p][q] * bf2f(att[row * PAD + p * 16 + c]);
            sp += __shfl_xor(sp, 1);
            sp += __shfl_xor(sp, 2);
            sp += __shfl_xor(sp, 4);
            sp += __shfl_xor(sp, 8);
            if (c == 0 && row < nq) qout[row] = sp;
        }
}

// ================= per-pair kernel: 2 waves, contiguous tile load =================
__global__ __launch_bounds__(128) void pair_kernel(const u16* __restrict__ Gt,
                                                   const u16* __restrict__ SSb,
                                                   const u16* __restrict__ IIb,
                                                   const float* __restrict__ SSd,
                                                   const float* __restrict__ IId,
                                                   const int* __restrict__ s_l,
                                                   float* __restrict__ score1,
                                                   float* __restrict__ score2,
                                                   float* __restrict__ dAp,
                                                   float* __restrict__ dBp) {
    int j = blockIdx.x, i = blockIdx.y;
    int t = threadIdx.x, lane = t & 63, wid = t >> 6;
    __shared__ __align__(16) u16 glb[Rr * 44];      // g bf16, pitch 44
    __shared__ __align__(16) u16 attA[48 * PAD];    // [r][w] unnormalized e
    __shared__ __align__(16) u16 attB[48 * PAD];    // [w][r] unnormalized e
    __shared__ float invA[Ww], invB[Rr], sA[Rr], sB[Ww], qA[Rr], qB[Ww];
    int L = s_l[j];

    // ---- P0: zero att arrays; contiguous G-tile load (all 128 lanes) ----
    {
        uint* za = (uint*)attA;
        uint* zb = (uint*)attB;
#pragma unroll
        for (int k = 0; k < 14; ++k) {
            int idx = t + k * 128;
            if (idx < 48 * PAD / 2) { za[idx] = 0; zb[idx] = 0; }
        }
        const u16* gt = Gt + (size_t)(i * Bn + j) * TSZ;
        for (int c = t; c < 180; c += 128) {   // 180 chunks of 8 u16
            int r = c / 5, q = c - (c / 5) * 5;
            uint4 v = *(const uint4*)(gt + c * 8);
            *(uint2*)&glb[r * 44 + q * 8] = make_uint2(v.x, v.y);
            *(uint2*)&glb[r * 44 + q * 8 + 4] = make_uint2(v.z, v.w);
        }
    }
    float iid = 0.f, ssd = 0.f;
    if (wid == 0 && lane < Rr) iid = IId[i * Rr + lane];
    if (wid == 1 && lane < Ww) ssd = SSd[j * Ww + lane];
    __syncthreads();

    // ---- P1: norms ----
    if (wid == 0 && lane < Rr) {
        float sum = 0.f;
#pragma unroll 8
        for (int w = 0; w < Ww; ++w) {
            float x = bf2f(glb[lane * 44 + w]);
            x = x < 0.f ? 0.1f * x : x;
            sum += x * x;
        }
        invB[lane] = 9.f / (sqrtf(sum) + EPSf);
    }
    if (wid == 1 && lane < Ww) {
        float sum = 0.f;
#pragma unroll 6
        for (int r = 0; r < Rr; ++r) {
            float x = bf2f(glb[r * 44 + lane]);
            x = x < 0.f ? 0.1f * x : x;
            sum += x * x;
        }
        invA[lane] = 6.f / (sqrtf(sum) + EPSf);
    }
    __syncthreads();

    // ---- P2: softmax (no-max; args bounded) + fused dot ----
    float dot = 0.f, myinv = 0.f;
    if (wid == 0 && lane < Rr) {
        float ssum = 0.f;
#pragma unroll 8
        for (int w = 0; w < Ww; ++w) {
            float e = 0.f;
            if (w < L) {
                float gx = bf2f(glb[lane * 44 + w]);
                float x = gx < 0.f ? 0.1f * gx : gx;
                e = __expf(x * invA[w]);
                dot += e * gx;
            }
            attA[lane * PAD + w] = f2bf(e);
            ssum += e;
        }
        myinv = 1.f / ssum;
        dot *= myinv;
        sA[lane] = myinv;
    }
    if (wid == 1 && lane < Ww) {
        float ssum = 0.f;
#pragma unroll 6
        for (int r = 0; r < Rr; ++r) {
            float gx = bf2f(glb[r * 44 + lane]);
            float x = gx < 0.f ? 0.1f * gx : gx;
            float e = __expf(x * invB[r]);
            dot += e * gx;
            attB[lane * PAD + r] = f2bf(e);
            ssum += e;
        }
        myinv = 1.f / ssum;
        dot *= myinv;
        sB[lane] = myinv;
    }
    __syncthreads();

    // ---- P3: MFMA quadratic forms ----
    if (wid == 0)
        quad_mfma(attA, SSb + (size_t)j * 48 * SBP, qA, Rr, lane);
    else
        quad_mfma(attB, IIb + (size_t)i * 48 * SBP, qB, Ww, lane);

    // ---- P4: sims + LSE ----
    if (wid == 0) {
        float e1 = 0.f;
        if (lane < Rr) {
            float q = qA[lane] * myinv * myinv;
            float s1 = dot / fmaxf(sqrtf(iid) * sqrtf(fmaxf(q, 0.f)), EPSf);
            e1 = __expf(6.f * s1);
        }
#pragma unroll
        for (int off = 1; off < 64; off <<= 1) e1 += __shfl_xor(e1, off);
        if (lane == 0) score1[i * Bn + j] = __logf(e1) * (1.f / 6.f);
    } else {
        float e2 = 0.f;
        if (lane < Ww) {
            float q = qB[lane] * myinv * myinv;
            float s2 = dot / fmaxf(sqrtf(ssd) * sqrtf(fmaxf(q, 0.f)), EPSf);
            e2 = (lane < L) ? __expf(6.f * s2) : 0.f;
        }
#pragma unroll
        for (int off = 1; off < 64; off <<= 1) e2 += __shfl_xor(e2, off);
        if (lane == 0) score2[i * Bn + j] = __logf(e2) * (1.f / 6.f);
    }

    // ---- diag coefficients ----
    if (i == j) {
        __syncthreads();
        if (wid == 1 && lane < Ww) {
            float sum = 0.f;
#pragma unroll 6
            for (int r = 0; r < Rr; ++r) sum += bf2f(attA[r * PAD + lane]) * sA[r];
            dAp[i * Ww + lane] = sum * (1.f / (float)Rr);
        }
        if (wid == 0 && lane < Rr) {
            float sum = 0.f;
            for (int w = 0; w < L; ++w) sum += bf2f(attB[w * PAD + lane]) * sB[w];
            dBp[i * Rr + lane] = sum / (float)L;
        }
    }
}

// ============ diagonal outputs (vectorized bf16x8) + fused hinge loss ============
__global__ __launch_bounds__(128) void diag_out_kernel(const u16* __restrict__ Ab,
                                                       const u16* __restrict__ Bb,
                                                       const int* __restrict__ s_l,
                                                       const float* __restrict__ dA,
                                                       const float* __restrict__ dB,
                                                       const float* __restrict__ score1,
                                                       const float* __restrict__ score2,
                                                       float* __restrict__ out) {
    int t = threadIdx.x;
    int bi = blockIdx.x;
    if (bi == Bn) {
        __shared__ float sc[Bn][Bn + 1];
        for (int idx = t; idx < Bn * Bn; idx += 128)
            sc[idx >> 6][idx & 63] = 0.5f * (score1[idx] + score2[idx]);
        __syncthreads();
        if (t < 64) {
            float dt = sc[t][t];
            float rowmax = 0.f, colmax = 0.f;
            for (int k = 0; k < Bn; ++k) {
                if (k != t) {
                    rowmax = fmaxf(rowmax, 0.2f + sc[t][k] - dt);
                    colmax = fmaxf(colmax, 0.2f + sc[k][t] - dt);
                }
            }
            float v = rowmax + colmax;
            for (int off = 32; off; off >>= 1) v += __shfl_down(v, off);
            if (t == 0) out[0] = v;
        }
        return;
    }
    int i = bi;
    int L = s_l[i];
    __shared__ float aw[Ww], br[Rr];
    if (t < Ww) aw[t] = dA[i * Ww + t];
    if (t >= 64 && t < 64 + Rr) br[t - 64] = dB[i * Rr + (t - 64)];
    __syncthreads();
    int d0 = t * 8;
    const u16* BbI = Bb + (size_t)i * Ww * Dd + d0;
    const u16* AbI = Ab + (size_t)i * Rr * Dd + d0;
    float a1[8], a2[8];
#pragma unroll
    for (int k = 0; k < 8; ++k) { a1[k] = 0.f; a2[k] = 0.f; }
    for (int w = 0; w < L; ++w) {
        bf16x8 v = *(const bf16x8*)(BbI + (size_t)w * Dd);
        float c = aw[w];
#pragma unroll
        for (int k = 0; k < 8; ++k) a1[k] += c * bf2f((u16)v[k]);
    }
#pragma unroll 6
    for (int r = 0; r < Rr; ++r) {
        bf16x8 v = *(const bf16x8*)(AbI + (size_t)r * Dd);
        float c = br[r];
#pragma unroll
        for (int k = 0; k < 8; ++k) a2[k] += c * bf2f((u16)v[k]);
    }
    float* o1 = out + 1 + (size_t)i * Dd + d0;
    float* o2 = out + 1 + (size_t)Bn * Dd + (size_t)i * Dd + d0;
#pragma unroll
    for (int k = 0; k < 8; ++k) { o1[k] = a1[k]; o2[k] = a2[k]; }
}

extern "C" void kernel_launch(void* const* d_in, const int* in_sizes, int n_in,
                              void* d_out, int out_size, void* d_ws, size_t ws_size,
                              hipStream_t stream) {
    const float* im = (const float*)d_in[0];
    const float* s = (const float*)d_in[1];
    const int* s_l = (const int*)d_in[2];
    float* out = (float*)d_out;

    u16* Ab = (u16*)d_ws;                         // GM*Dd
    u16* Bb = Ab + (size_t)GM * Dd;               // GN*Dd
    u16* Gt = Bb + (size_t)GN * Dd;               // GM*GN (tiled: 4096 x 1440)
    u16* SSb = Gt + (size_t)GM * GN;              // 64*48*64
    u16* IIb = SSb + (size_t)Bn * 48 * SBP;       // 64*48*64
    float* SSd = (float*)(IIb + (size_t)Bn * 48 * SBP);
    float* IId = SSd + (size_t)Bn * Ww;
    float* score1 = IId + (size_t)Bn * Rr;
    float* score2 = score1 + Bn * Bn;
    float* dA = score2 + Bn * Bn;
    float* dB = dA + Bn * Ww;

    prep_kernel<<<NCONV + 2 * Bn, 256, 0, stream>>>(im, s, s_l, Ab, Bb, SSb, IIb, SSd, IId);

    dim3 ggrid(GN / 128, GM / 64);
    gemm_mfma_kernel<<<ggrid, 256, 0, stream>>>(Ab, Bb, Gt);

    dim3 pgrid(Bn, Bn);
    pair_kernel<<<pgrid, 128, 0, stream>>>(Gt, SSb, IIb, SSd, IId, s_l,
                                           score1, score2, dA, dB);

    diag_out_kernel<<<Bn + 1, 128, 0, stream>>>(Ab, Bb, s_l, dA, dB, score1, score2, out);
}

// Round 12
// 76.548 us; speedup vs baseline: 1.0312x; 1.0312x over previous
//
#include <hip/hip_runtime.h>
#include <math.h>

#define Bn 64
#define Rr 36
#define Ww 40
#define Dd 1024
#define GM 2304   // Bn*Rr
#define GN 2560   // Bn*Ww
#define NCONV 4864  // (GM*Dd + GN*Dd)/4/256
#define PAD 72      // att LDS pitch (u16)
#define SBP 64      // SSb/IIb global pitch (u16)
#define TSZ 1440    // G tile size in u16 (36*40)
#define EPSf 1e-8f

typedef unsigned short u16;
typedef __attribute__((ext_vector_type(8))) short bf16x8;
typedef __attribute__((ext_vector_type(4))) float f32x4;

struct alignas(8) U16x4 { u16 x, y, z, w; };

__device__ inline u16 f2bf(float x) {
    unsigned int u = __float_as_uint(x);
    u += 0x7FFFu + ((u >> 16) & 1u);
    return (u16)(u >> 16);
}
__device__ inline float bf2f(u16 h) {
    return __uint_as_float(((unsigned int)h) << 16);
}

__device__ __forceinline__ void gl_lds16(const u16* g, u16* l) {
    __builtin_amdgcn_global_load_lds(
        (const __attribute__((address_space(1))) void*)g,
        (__attribute__((address_space(3))) void*)l, 16, 0, 0);
}

// ================= convert: fp32 -> bf16 (mask s rows) =================
__global__ __launch_bounds__(256) void convert_kernel(const float* __restrict__ im,
                                                      const float* __restrict__ s,
                                                      const int* __restrict__ s_l,
                                                      u16* __restrict__ Ab,
                                                      u16* __restrict__ Bb) {
    const int nA4 = GM * Dd / 4;
    int idx = blockIdx.x * 256 + threadIdx.x;
    if (idx < nA4) {
        float4 v = *(const float4*)(im + (size_t)idx * 4);
        U16x4 o = {f2bf(v.x), f2bf(v.y), f2bf(v.z), f2bf(v.w)};
        *(U16x4*)(Ab + (size_t)idx * 4) = o;
    } else {
        int i2 = idx - nA4;
        int f = i2 * 4;
        int row = f >> 10;
        int j = row / Ww, w = row - j * Ww;
        U16x4 o = {0, 0, 0, 0};
        if (w < s_l[j]) {
            float4 v = *(const float4*)(s + (size_t)f);
            o.x = f2bf(v.x); o.y = f2bf(v.y); o.z = f2bf(v.z); o.w = f2bf(v.w);
        }
        *(U16x4*)(Bb + (size_t)i2 * 4) = o;
    }
}

// ====== merged kernel: gemm (bm<36) + grams (bm>=36), shared-memory union ======
// gemm: 64x128 tile, BK=64, XOR swizzle, 2-buffer dbuf, tiled Gt epilogue.
// gram: 4-wave K-split MFMA from bf16 Ab/Bb, bf16-padded output + fp32 diag.
__global__ __launch_bounds__(256) void gemm_gram_kernel(const u16* __restrict__ Ab,
                                                        const u16* __restrict__ Bb,
                                                        u16* __restrict__ Gt,
                                                        u16* __restrict__ SSb,
                                                        u16* __restrict__ IIb,
                                                        float* __restrict__ SSd,
                                                        float* __restrict__ IId) {
    __shared__ __align__(16) char smem[49152];
    int bn = blockIdx.x;
    int bm = blockIdx.y;
    int t = threadIdx.x;
    int lane = t & 63, wid = t >> 6;

    if (bm >= 36) {
        // ---------------- gram branch (128 blocks of the 140 extra) ----------------
        int gb = (bm - 36) * 20 + bn;
        if (gb >= 2 * Bn) return;
        bool isS = gb < Bn;
        int idx = isS ? gb : gb - Bn;
        int n = isS ? Ww : Rr;
        const u16* base = isS ? (Bb + (size_t)idx * Ww * Dd) : (Ab + (size_t)idx * Rr * Dd);
        u16* outb = isS ? (SSb + (size_t)idx * 48 * SBP) : (IIb + (size_t)idx * 48 * SBP);
        float* outd = isS ? (SSd + (size_t)idx * Ww) : (IId + (size_t)idx * Rr);
        float* red = (float*)smem;   // [3][64][37]
        int frow = lane & 15, fk = (lane >> 4) * 8;

        f32x4 acc[3][3];
        for (int m = 0; m < 3; ++m)
            for (int p = 0; p < 3; ++p) acc[m][p] = (f32x4){0.f, 0.f, 0.f, 0.f};

        for (int ks = 0; ks < 8; ++ks) {
            int k0 = wid * 256 + ks * 32 + fk;
            bf16x8 f[3];
            for (int m = 0; m < 3; ++m) {
                int rr = m * 16 + frow;
                if (rr >= n) rr = n - 1;     // clamp; garbage cells are annihilated
                f[m] = *(const bf16x8*)(base + (size_t)rr * Dd + k0);
            }
            for (int m = 0; m < 3; ++m)
                for (int p = 0; p < 3; ++p)
                    acc[m][p] = __builtin_amdgcn_mfma_f32_16x16x32_bf16(f[m], f[p], acc[m][p], 0, 0, 0);
        }
        if (wid) {
            for (int m = 0; m < 3; ++m)
                for (int p = 0; p < 3; ++p)
                    for (int q = 0; q < 4; ++q)
                        red[(wid - 1) * 64 * 37 + lane * 37 + (m * 3 + p) * 4 + q] = acc[m][p][q];
        }
        __syncthreads();
        if (wid == 0) {
            for (int wv = 0; wv < 3; ++wv)
                for (int m = 0; m < 3; ++m)
                    for (int p = 0; p < 3; ++p)
                        for (int q = 0; q < 4; ++q)
                            acc[m][p][q] += red[wv * 64 * 37 + lane * 37 + (m * 3 + p) * 4 + q];
            int crow = (lane >> 4) * 4, ccol = lane & 15;
            for (int m = 0; m < 3; ++m)
                for (int p = 0; p < 3; ++p)
                    for (int q = 0; q < 4; ++q) {
                        int row = m * 16 + crow + q;
                        int col = p * 16 + ccol;
                        float v = acc[m][p][q];
                        outb[row * SBP + col] = f2bf(v);
                        if (row == col && row < n) outd[row] = v;
                    }
        }
        return;
    }

    // ---------------- gemm branch ----------------
    u16* As = (u16*)smem;             // [2][64][64]  : BI*4096 + row*64
    u16* Bs = (u16*)(smem + 16384);   // [2][128][64] : BI*8192 + row*64
    int wr = wid >> 1, wc = wid & 1;

    int lrow8 = lane >> 3;
    int sslot = (lane & 7) ^ lrow8;   // pre-swizzled global source, linear LDS dest
    const u16* ga = Ab + ((size_t)(bm * 64 + wid * 16) + lrow8) * Dd + sslot * 8;
    const u16* gb = Bb + ((size_t)(bn * 128 + wid * 32) + lrow8) * Dd + sslot * 8;

    f32x4 acc[2][4];
    for (int m = 0; m < 2; ++m)
        for (int n = 0; n < 4; ++n) acc[m][n] = (f32x4){0.f, 0.f, 0.f, 0.f};

    int frow = lane & 15;
    int cgr = lane >> 4;

#define STAGE(BI, KK) do { \
        gl_lds16(ga + (KK), As + (BI) * 4096 + (wid * 16) * 64); \
        gl_lds16(ga + (size_t)8 * Dd + (KK), As + (BI) * 4096 + (wid * 16 + 8) * 64); \
        gl_lds16(gb + (KK), Bs + (BI) * 8192 + (wid * 32) * 64); \
        gl_lds16(gb + (size_t)8 * Dd + (KK), Bs + (BI) * 8192 + (wid * 32 + 8) * 64); \
        gl_lds16(gb + (size_t)16 * Dd + (KK), Bs + (BI) * 8192 + (wid * 32 + 16) * 64); \
        gl_lds16(gb + (size_t)24 * Dd + (KK), Bs + (BI) * 8192 + (wid * 32 + 24) * 64); \
    } while (0)

    STAGE(0, 0);
    for (int step = 0; step < 16; ++step) {
        int cur = step & 1;
        __syncthreads();
        if (step < 15) STAGE(cur ^ 1, (step + 1) * 64);
        bf16x8 af[2][2], bf[4][2];
#pragma unroll
        for (int m = 0; m < 2; ++m) {
            int row = wr * 32 + m * 16 + frow;
#pragma unroll
            for (int ks = 0; ks < 2; ++ks) {
                int slot = (ks * 4 + cgr) ^ (row & 7);
                af[m][ks] = *(const bf16x8*)(As + cur * 4096 + row * 64 + slot * 8);
            }
        }
#pragma unroll
        for (int n = 0; n < 4; ++n) {
            int row = wc * 64 + n * 16 + frow;
#pragma unroll
            for (int ks = 0; ks < 2; ++ks) {
                int slot = (ks * 4 + cgr) ^ (row & 7);
                bf[n][ks] = *(const bf16x8*)(Bs + cur * 8192 + row * 64 + slot * 8);
            }
        }
#pragma unroll
        for (int ks = 0; ks < 2; ++ks)
#pragma unroll
            for (int m = 0; m < 2; ++m)
#pragma unroll
                for (int n = 0; n < 4; ++n)
                    acc[m][n] = __builtin_amdgcn_mfma_f32_16x16x32_bf16(af[m][ks], bf[n][ks], acc[m][n], 0, 0, 0);
    }
#undef STAGE

    // epilogue: scatter into pair-tile-major layout Gt[(i*64+j)][r][w]
    int crow0 = bm * 64 + wr * 32 + (lane >> 4) * 4;
    int ccol0 = bn * 128 + wc * 64 + (lane & 15);
    int tjv[4], wv[4];
#pragma unroll
    for (int n = 0; n < 4; ++n) {
        int col = ccol0 + n * 16;
        tjv[n] = col / 40;
        wv[n] = col - tjv[n] * 40;
    }
    for (int m = 0; m < 2; ++m)
        for (int q = 0; q < 4; ++q) {
            int row = crow0 + m * 16 + q;
            int ti = row / 36, r2 = row - ti * 36;
            u16* dstbase = Gt + (size_t)ti * Bn * TSZ + (size_t)r2 * 40;
            for (int n = 0; n < 4; ++n)
                dstbase[(size_t)tjv[n] * TSZ + wv[n]] = f2bf(acc[m][n][q]);
        }
}

// ---- quadratic form via MFMA: q[row] = e_row^T M e_row ----
__device__ __forceinline__ void quad_mfma(const u16* att, const u16* M,
                                          float* qout, int nq, int lane) {
    int c = lane & 15, g4 = lane >> 4;
    f32x4 acc[3][3];
#pragma unroll
    for (int m = 0; m < 3; ++m)
#pragma unroll
        for (int p = 0; p < 3; ++p) acc[m][p] = (f32x4){0.f, 0.f, 0.f, 0.f};
#pragma unroll
    for (int ks = 0; ks < 2; ++ks) {
        bf16x8 fa[3], fb[3];
#pragma unroll
        for (int m = 0; m < 3; ++m)
            fa[m] = *(const bf16x8*)&att[(m * 16 + c) * PAD + g4 * 8 + ks * 32];
#pragma unroll
        for (int p = 0; p < 3; ++p)
            fb[p] = *(const bf16x8*)(M + (size_t)(p * 16 + c) * SBP + g4 * 8 + ks * 32);
#pragma unroll
        for (int m = 0; m < 3; ++m)
#pragma unroll
            for (int p = 0; p < 3; ++p)
                acc[m][p] = __builtin_amdgcn_mfma_f32_16x16x32_bf16(fa[m], fb[p], acc[m][p], 0, 0, 0);
    }
#pragma unroll
    for (int m = 0; m < 3; ++m)
#pragma unroll
        for (int q = 0; q < 4; ++q) {
            int row = m * 16 + g4 * 4 + q;
            float sp = 0.f;
#pragma unroll
            for (int p = 0; p < 3; ++p)
                sp += acc[m][p][q] * bf2f(att[row * PAD + p * 16 + c]);
            sp += __shfl_xor(sp, 1);
            sp += __shfl_xor(sp, 2);
            sp += __shfl_xor(sp, 4);
            sp += __shfl_xor(sp, 8);
            if (c == 0 && row < nq) qout[row] = sp;
        }
}

// ====== per-pair kernel: 2 waves, contiguous tile load, diag outputs folded ======
__global__ __launch_bounds__(128) void pair_kernel(const u16* __restrict__ Gt,
                                                   const u16* __restrict__ SSb,
                                                   const u16* __restrict__ IIb,
                                                   const float* __restrict__ SSd,
                                                   const float* __restrict__ IId,
                                                   const u16* __restrict__ Ab,
                                                   const u16* __restrict__ Bb,
                                                   const int* __restrict__ s_l,
                                                   float* __restrict__ score1,
                                                   float* __restrict__ score2,
                                                   float* __restrict__ out) {
    int j = blockIdx.x, i = blockIdx.y;
    int t = threadIdx.x, lane = t & 63, wid = t >> 6;
    __shared__ __align__(16) u16 glb[Rr * 44];      // g bf16, pitch 44
    __shared__ __align__(16) u16 attA[48 * PAD];    // [r][w] unnormalized e
    __shared__ __align__(16) u16 attB[48 * PAD];    // [w][r] unnormalized e
    __shared__ float invA[Ww], invB[Rr], sA[Rr], sB[Ww], qA[Rr], qB[Ww];
    __shared__ float aw[Ww], br[Rr];
    int L = s_l[j];

    // ---- P0: zero att arrays; contiguous G-tile load (all 128 lanes) ----
    {
        uint* za = (uint*)attA;
        uint* zb = (uint*)attB;
#pragma unroll
        for (int k = 0; k < 14; ++k) {
            int idx = t + k * 128;
            if (idx < 48 * PAD / 2) { za[idx] = 0; zb[idx] = 0; }
        }
        const u16* gt = Gt + (size_t)(i * Bn + j) * TSZ;
        for (int c = t; c < 180; c += 128) {   // 180 chunks of 8 u16
            int r = c / 5, q = c - (c / 5) * 5;
            uint4 v = *(const uint4*)(gt + c * 8);
            *(uint2*)&glb[r * 44 + q * 8] = make_uint2(v.x, v.y);
            *(uint2*)&glb[r * 44 + q * 8 + 4] = make_uint2(v.z, v.w);
        }
    }
    float iid = 0.f, ssd = 0.f;
    if (wid == 0 && lane < Rr) iid = IId[i * Rr + lane];
    if (wid == 1 && lane < Ww) ssd = SSd[j * Ww + lane];
    __syncthreads();

    // ---- P1: norms ----
    if (wid == 0 && lane < Rr) {
        float sum = 0.f;
#pragma unroll 8
        for (int w = 0; w < Ww; ++w) {
            float x = bf2f(glb[lane * 44 + w]);
            x = x < 0.f ? 0.1f * x : x;
            sum += x * x;
        }
        invB[lane] = 9.f / (sqrtf(sum) + EPSf);
    }
    if (wid == 1 && lane < Ww) {
        float sum = 0.f;
#pragma unroll 6
        for (int r = 0; r < Rr; ++r) {
            float x = bf2f(glb[r * 44 + lane]);
            x = x < 0.f ? 0.1f * x : x;
            sum += x * x;
        }
        invA[lane] = 6.f / (sqrtf(sum) + EPSf);
    }
    __syncthreads();

    // ---- P2: softmax (no-max; args bounded) + fused dot ----
    float dot = 0.f, myinv = 0.f;
    if (wid == 0 && lane < Rr) {
        float ssum = 0.f;
#pragma unroll 8
        for (int w = 0; w < Ww; ++w) {
            float e = 0.f;
            if (w < L) {
                float gx = bf2f(glb[lane * 44 + w]);
                float x = gx < 0.f ? 0.1f * gx : gx;
                e = __expf(x * invA[w]);
                dot += e * gx;
            }
            attA[lane * PAD + w] = f2bf(e);
            ssum += e;
        }
        myinv = 1.f / ssum;
        dot *= myinv;
        sA[lane] = myinv;
    }
    if (wid == 1 && lane < Ww) {
        float ssum = 0.f;
#pragma unroll 6
        for (int r = 0; r < Rr; ++r) {
            float gx = bf2f(glb[r * 44 + lane]);
            float x = gx < 0.f ? 0.1f * gx : gx;
            float e = __expf(x * invB[r]);
            dot += e * gx;
            attB[lane * PAD + r] = f2bf(e);
            ssum += e;
        }
        myinv = 1.f / ssum;
        dot *= myinv;
        sB[lane] = myinv;
    }
    __syncthreads();

    // ---- P3: MFMA quadratic forms ----
    if (wid == 0)
        quad_mfma(attA, SSb + (size_t)j * 48 * SBP, qA, Rr, lane);
    else
        quad_mfma(attB, IIb + (size_t)i * 48 * SBP, qB, Ww, lane);

    // ---- P4: sims + LSE ----
    if (wid == 0) {
        float e1 = 0.f;
        if (lane < Rr) {
            float q = qA[lane] * myinv * myinv;
            float s1 = dot / fmaxf(sqrtf(iid) * sqrtf(fmaxf(q, 0.f)), EPSf);
            e1 = __expf(6.f * s1);
        }
#pragma unroll
        for (int off = 1; off < 64; off <<= 1) e1 += __shfl_xor(e1, off);
        if (lane == 0) score1[i * Bn + j] = __logf(e1) * (1.f / 6.f);
    } else {
        float e2 = 0.f;
        if (lane < Ww) {
            float q = qB[lane] * myinv * myinv;
            float s2 = dot / fmaxf(sqrtf(ssd) * sqrtf(fmaxf(q, 0.f)), EPSf);
            e2 = (lane < L) ? __expf(6.f * s2) : 0.f;
        }
#pragma unroll
        for (int off = 1; off < 64; off <<= 1) e2 += __shfl_xor(e2, off);
        if (lane == 0) score2[i * Bn + j] = __logf(e2) * (1.f / 6.f);
    }

    // ---- diag blocks: coefficients + vectorized output streaming ----
    if (i == j) {
        __syncthreads();
        if (wid == 1 && lane < Ww) {
            float sum = 0.f;
#pragma unroll 6
            for (int r = 0; r < Rr; ++r) sum += bf2f(attA[r * PAD + lane]) * sA[r];
            aw[lane] = sum * (1.f / (float)Rr);
        }
        if (wid == 0 && lane < Rr) {
            float sum = 0.f;
            for (int w = 0; w < L; ++w) sum += bf2f(attB[w * PAD + lane]) * sB[w];
            br[lane] = sum / (float)L;
        }
        __syncthreads();
        int d0 = t * 8;
        const u16* BbI = Bb + (size_t)i * Ww * Dd + d0;
        const u16* AbI = Ab + (size_t)i * Rr * Dd + d0;
        float a1[8], a2[8];
#pragma unroll
        for (int k = 0; k < 8; ++k) { a1[k] = 0.f; a2[k] = 0.f; }
        for (int w = 0; w < L; ++w) {
            bf16x8 v = *(const bf16x8*)(BbI + (size_t)w * Dd);
            float c = aw[w];
#pragma unroll
            for (int k = 0; k < 8; ++k) a1[k] += c * bf2f((u16)v[k]);
        }
#pragma unroll 6
        for (int r = 0; r < Rr; ++r) {
            bf16x8 v = *(const bf16x8*)(AbI + (size_t)r * Dd);
            float c = br[r];
#pragma unroll
            for (int k = 0; k < 8; ++k) a2[k] += c * bf2f((u16)v[k]);
        }
        float* o1 = out + 1 + (size_t)i * Dd + d0;
        float* o2 = out + 1 + (size_t)Bn * Dd + (size_t)i * Dd + d0;
#pragma unroll
        for (int k = 0; k < 8; ++k) { o1[k] = a1[k]; o2[k] = a2[k]; }
    }
}

// ================= hinge loss =================
__global__ void loss_kernel(const float* __restrict__ s1,
                            const float* __restrict__ s2,
                            float* __restrict__ out) {
    int t = threadIdx.x;
    __shared__ float sc[Bn][Bn + 1];
    for (int idx = t; idx < Bn * Bn; idx += 64)
        sc[idx >> 6][idx & 63] = 0.5f * (s1[idx] + s2[idx]);
    __syncthreads();
    float dt = sc[t][t];
    float rowmax = 0.f, colmax = 0.f;
    for (int k = 0; k < Bn; ++k) {
        if (k != t) {
            float cs = 0.2f + sc[t][k] - dt;
            if (cs > rowmax) rowmax = cs;
            float ci = 0.2f + sc[k][t] - dt;
            if (ci > colmax) colmax = ci;
        }
    }
    float v = rowmax + colmax;
    for (int off = 32; off; off >>= 1) v += __shfl_down(v, off);
    if (t == 0) out[0] = v;
}

extern "C" void kernel_launch(void* const* d_in, const int* in_sizes, int n_in,
                              void* d_out, int out_size, void* d_ws, size_t ws_size,
                              hipStream_t stream) {
    const float* im = (const float*)d_in[0];
    const float* s = (const float*)d_in[1];
    const int* s_l = (const int*)d_in[2];
    float* out = (float*)d_out;

    u16* Ab = (u16*)d_ws;                         // GM*Dd
    u16* Bb = Ab + (size_t)GM * Dd;               // GN*Dd
    u16* Gt = Bb + (size_t)GN * Dd;               // GM*GN (tiled: 4096 x 1440)
    u16* SSb = Gt + (size_t)GM * GN;              // 64*48*64
    u16* IIb = SSb + (size_t)Bn * 48 * SBP;       // 64*48*64
    float* SSd = (float*)(IIb + (size_t)Bn * 48 * SBP);
    float* IId = SSd + (size_t)Bn * Ww;
    float* score1 = IId + (size_t)Bn * Rr;
    float* score2 = score1 + Bn * Bn;

    convert_kernel<<<NCONV, 256, 0, stream>>>(im, s, s_l, Ab, Bb);

    dim3 ggrid(GN / 128, 36 + 7);   // bm<36: gemm tiles; bm>=36: 128 gram blocks
    gemm_gram_kernel<<<ggrid, 256, 0, stream>>>(Ab, Bb, Gt, SSb, IIb, SSd, IId);

    dim3 pgrid(Bn, Bn);
    pair_kernel<<<pgrid, 128, 0, stream>>>(Gt, SSb, IIb, SSd, IId, Ab, Bb, s_l,
                                           score1, score2, out);

    loss_kernel<<<1, 64, 0, stream>>>(score1, score2, out);
}

// Round 13
// 72.495 us; speedup vs baseline: 1.0888x; 1.0559x over previous
//
#include <hip/hip_runtime.h>
#include <math.h>

#define Bn 64
#define Rr 36
#define Ww 40
#define Dd 1024
#define GM 2304   // Bn*Rr
#define GN 2560   // Bn*Ww
#define NCONV 4864  // (GM*Dd + GN*Dd)/4/256
#define PAD 72      // att LDS pitch (u16)
#define SBP 64      // SSb/IIb global pitch (u16)
#define TSZ 1440    // G tile size in u16 (36*40)
#define EPSf 1e-8f

typedef unsigned short u16;
typedef __attribute__((ext_vector_type(8))) short bf16x8;
typedef __attribute__((ext_vector_type(4))) float f32x4;

struct alignas(8) U16x4 { u16 x, y, z, w; };

__device__ inline u16 f2bf(float x) {
    unsigned int u = __float_as_uint(x);
    u += 0x7FFFu + ((u >> 16) & 1u);
    return (u16)(u >> 16);
}
__device__ inline float bf2f(u16 h) {
    return __uint_as_float(((unsigned int)h) << 16);
}

__device__ __forceinline__ void gl_lds16(const u16* g, u16* l) {
    __builtin_amdgcn_global_load_lds(
        (const __attribute__((address_space(1))) void*)g,
        (__attribute__((address_space(3))) void*)l, 16, 0, 0);
}

// ================= convert: fp32 -> bf16 (mask s rows) =================
__global__ __launch_bounds__(256) void convert_kernel(const float* __restrict__ im,
                                                      const float* __restrict__ s,
                                                      const int* __restrict__ s_l,
                                                      u16* __restrict__ Ab,
                                                      u16* __restrict__ Bb) {
    const int nA4 = GM * Dd / 4;
    int idx = blockIdx.x * 256 + threadIdx.x;
    if (idx < nA4) {
        float4 v = *(const float4*)(im + (size_t)idx * 4);
        U16x4 o = {f2bf(v.x), f2bf(v.y), f2bf(v.z), f2bf(v.w)};
        *(U16x4*)(Ab + (size_t)idx * 4) = o;
    } else {
        int i2 = idx - nA4;
        int f = i2 * 4;
        int row = f >> 10;
        int j = row / Ww, w = row - j * Ww;
        U16x4 o = {0, 0, 0, 0};
        if (w < s_l[j]) {
            float4 v = *(const float4*)(s + (size_t)f);
            o.x = f2bf(v.x); o.y = f2bf(v.y); o.z = f2bf(v.z); o.w = f2bf(v.w);
        }
        *(U16x4*)(Bb + (size_t)i2 * 4) = o;
    }
}

// == merged: gemm 128x128 L2-resident 2D-XCD partition (bid<360) + grams (bid>=360) ==
// gemm: XCD x = bid%8 owns bm in [9*(x>>2), +9), bn in [5*(x&3), +5):
//       per-XCD footprint 2.3MB A + 1.3MB B < 4MB L2 -> staging at L2 rate.
__global__ __launch_bounds__(256) void gemm_gram_kernel(const u16* __restrict__ Ab,
                                                        const u16* __restrict__ Bb,
                                                        u16* __restrict__ Gt,
                                                        u16* __restrict__ SSb,
                                                        u16* __restrict__ IIb,
                                                        float* __restrict__ SSd,
                                                        float* __restrict__ IId) {
    __shared__ __align__(16) char smem[65536];
    int bid = blockIdx.x;
    int t = threadIdx.x;
    int lane = t & 63, wid = t >> 6;

    if (bid >= 360) {
        // ---------------- gram branch (128 blocks) ----------------
        int gb = bid - 360;
        bool isS = gb < Bn;
        int idx = isS ? gb : gb - Bn;
        int n = isS ? Ww : Rr;
        const u16* base = isS ? (Bb + (size_t)idx * Ww * Dd) : (Ab + (size_t)idx * Rr * Dd);
        u16* outb = isS ? (SSb + (size_t)idx * 48 * SBP) : (IIb + (size_t)idx * 48 * SBP);
        float* outd = isS ? (SSd + (size_t)idx * Ww) : (IId + (size_t)idx * Rr);
        float* red = (float*)smem;   // [3][64][37]
        int frow = lane & 15, fk = (lane >> 4) * 8;

        f32x4 acc[3][3];
        for (int m = 0; m < 3; ++m)
            for (int p = 0; p < 3; ++p) acc[m][p] = (f32x4){0.f, 0.f, 0.f, 0.f};

        for (int ks = 0; ks < 8; ++ks) {
            int k0 = wid * 256 + ks * 32 + fk;
            bf16x8 f[3];
            for (int m = 0; m < 3; ++m) {
                int rr = m * 16 + frow;
                if (rr >= n) rr = n - 1;     // clamp; garbage cells are annihilated
                f[m] = *(const bf16x8*)(base + (size_t)rr * Dd + k0);
            }
            for (int m = 0; m < 3; ++m)
                for (int p = 0; p < 3; ++p)
                    acc[m][p] = __builtin_amdgcn_mfma_f32_16x16x32_bf16(f[m], f[p], acc[m][p], 0, 0, 0);
        }
        if (wid) {
            for (int m = 0; m < 3; ++m)
                for (int p = 0; p < 3; ++p)
                    for (int q = 0; q < 4; ++q)
                        red[(wid - 1) * 64 * 37 + lane * 37 + (m * 3 + p) * 4 + q] = acc[m][p][q];
        }
        __syncthreads();
        if (wid == 0) {
            for (int wv = 0; wv < 3; ++wv)
                for (int m = 0; m < 3; ++m)
                    for (int p = 0; p < 3; ++p)
                        for (int q = 0; q < 4; ++q)
                            acc[m][p][q] += red[wv * 64 * 37 + lane * 37 + (m * 3 + p) * 4 + q];
            int crow = (lane >> 4) * 4, ccol = lane & 15;
            for (int m = 0; m < 3; ++m)
                for (int p = 0; p < 3; ++p)
                    for (int q = 0; q < 4; ++q) {
                        int row = m * 16 + crow + q;
                        int col = p * 16 + ccol;
                        float v = acc[m][p][q];
                        outb[row * SBP + col] = f2bf(v);
                        if (row == col && row < n) outd[row] = v;
                    }
        }
        return;
    }

    // ---------------- gemm branch: 128x128, BK=64, 2-buffer dbuf ----------------
    int xcd = bid & 7, local = bid >> 3;          // 45 blocks per XCD
    int lbm = local / 5, lbn = local - lbm * 5;
    int bm = (xcd >> 2) * 9 + lbm;                // 0..17
    int bn = (xcd & 3) * 5 + lbn;                 // 0..19

    u16* As = (u16*)smem;             // [2][128][64] : BI*8192 + row*64
    u16* Bs = (u16*)(smem + 32768);   // [2][128][64]
    int wr = wid >> 1, wc = wid & 1;

    int lrow8 = lane >> 3;
    int sslot = (lane & 7) ^ lrow8;   // pre-swizzled global source, linear LDS dest
    const u16* ga = Ab + ((size_t)(bm * 128 + wid * 32) + lrow8) * Dd + sslot * 8;
    const u16* gb = Bb + ((size_t)(bn * 128 + wid * 32) + lrow8) * Dd + sslot * 8;

    f32x4 acc[4][4];
    for (int m = 0; m < 4; ++m)
        for (int n = 0; n < 4; ++n) acc[m][n] = (f32x4){0.f, 0.f, 0.f, 0.f};

    int frow = lane & 15;
    int cgr = lane >> 4;

#define STAGE(BI, KK) do { \
        _Pragma("unroll") \
        for (int r8 = 0; r8 < 4; ++r8) { \
            gl_lds16(ga + (size_t)(r8 * 8) * Dd + (KK), As + (BI) * 8192 + (wid * 32 + r8 * 8) * 64); \
            gl_lds16(gb + (size_t)(r8 * 8) * Dd + (KK), Bs + (BI) * 8192 + (wid * 32 + r8 * 8) * 64); \
        } \
    } while (0)

    STAGE(0, 0);
    for (int step = 0; step < 16; ++step) {
        int cur = step & 1;
        __syncthreads();
        if (step < 15) STAGE(cur ^ 1, (step + 1) * 64);
        bf16x8 af[4][2], bf[4][2];
#pragma unroll
        for (int m = 0; m < 4; ++m) {
            int row = wr * 64 + m * 16 + frow;
#pragma unroll
            for (int ks = 0; ks < 2; ++ks) {
                int slot = (ks * 4 + cgr) ^ (row & 7);
                af[m][ks] = *(const bf16x8*)(As + cur * 8192 + row * 64 + slot * 8);
            }
        }
#pragma unroll
        for (int n = 0; n < 4; ++n) {
            int row = wc * 64 + n * 16 + frow;
#pragma unroll
            for (int ks = 0; ks < 2; ++ks) {
                int slot = (ks * 4 + cgr) ^ (row & 7);
                bf[n][ks] = *(const bf16x8*)(Bs + cur * 8192 + row * 64 + slot * 8);
            }
        }
#pragma unroll
        for (int ks = 0; ks < 2; ++ks)
#pragma unroll
            for (int m = 0; m < 4; ++m)
#pragma unroll
                for (int n = 0; n < 4; ++n)
                    acc[m][n] = __builtin_amdgcn_mfma_f32_16x16x32_bf16(af[m][ks], bf[n][ks], acc[m][n], 0, 0, 0);
    }
#undef STAGE

    // epilogue: scatter into pair-tile-major layout Gt[(i*64+j)][r][w]
    int crow0 = bm * 128 + wr * 64 + (lane >> 4) * 4;
    int ccol0 = bn * 128 + wc * 64 + (lane & 15);
    int tjv[4], wv[4];
#pragma unroll
    for (int n = 0; n < 4; ++n) {
        int col = ccol0 + n * 16;
        tjv[n] = col / 40;
        wv[n] = col - tjv[n] * 40;
    }
    for (int m = 0; m < 4; ++m)
        for (int q = 0; q < 4; ++q) {
            int row = crow0 + m * 16 + q;
            int ti = row / 36, r2 = row - ti * 36;
            u16* dstbase = Gt + (size_t)ti * Bn * TSZ + (size_t)r2 * 40;
            for (int n = 0; n < 4; ++n)
                dstbase[(size_t)tjv[n] * TSZ + wv[n]] = f2bf(acc[m][n][q]);
        }
}

// ---- quadratic form via MFMA: q[row] = e_row^T M e_row ----
__device__ __forceinline__ void quad_mfma(const u16* att, const u16* M,
                                          float* qout, int nq, int lane) {
    int c = lane & 15, g4 = lane >> 4;
    f32x4 acc[3][3];
#pragma unroll
    for (int m = 0; m < 3; ++m)
#pragma unroll
        for (int p = 0; p < 3; ++p) acc[m][p] = (f32x4){0.f, 0.f, 0.f, 0.f};
#pragma unroll
    for (int ks = 0; ks < 2; ++ks) {
        bf16x8 fa[3], fb[3];
#pragma unroll
        for (int m = 0; m < 3; ++m)
            fa[m] = *(const bf16x8*)&att[(m * 16 + c) * PAD + g4 * 8 + ks * 32];
#pragma unroll
        for (int p = 0; p < 3; ++p)
            fb[p] = *(const bf16x8*)(M + (size_t)(p * 16 + c) * SBP + g4 * 8 + ks * 32);
#pragma unroll
        for (int m = 0; m < 3; ++m)
#pragma unroll
            for (int p = 0; p < 3; ++p)
                acc[m][p] = __builtin_amdgcn_mfma_f32_16x16x32_bf16(fa[m], fb[p], acc[m][p], 0, 0, 0);
    }
#pragma unroll
    for (int m = 0; m < 3; ++m)
#pragma unroll
        for (int q = 0; q < 4; ++q) {
            int row = m * 16 + g4 * 4 + q;
            float sp = 0.f;
#pragma unroll
            for (int p = 0; p < 3; ++p)
                sp += acc[m][p][q] * bf2f(att[row * PAD + p * 16 + c]);
            sp += __shfl_xor(sp, 1);
            sp += __shfl_xor(sp, 2);
            sp += __shfl_xor(sp, 4);
            sp += __shfl_xor(sp, 8);
            if (c == 0 && row < nq) qout[row] = sp;
        }
}

// ====== per-pair kernel: 2 waves, contiguous tile load, diag outputs folded ======
__global__ __launch_bounds__(128) void pair_kernel(const u16* __restrict__ Gt,
                                                   const u16* __restrict__ SSb,
                                                   const u16* __restrict__ IIb,
                                                   const float* __restrict__ SSd,
                                                   const float* __restrict__ IId,
                                                   const u16* __restrict__ Ab,
                                                   const u16* __restrict__ Bb,
                                                   const int* __restrict__ s_l,
                                                   float* __restrict__ score1,
                                                   float* __restrict__ score2,
                                                   float* __restrict__ out) {
    int j = blockIdx.x, i = blockIdx.y;
    int t = threadIdx.x, lane = t & 63, wid = t >> 6;
    __shared__ __align__(16) u16 glb[Rr * 44];      // g bf16, pitch 44
    __shared__ __align__(16) u16 attA[48 * PAD];    // [r][w] unnormalized e
    __shared__ __align__(16) u16 attB[48 * PAD];    // [w][r] unnormalized e
    __shared__ float invA[Ww], invB[Rr], sA[Rr], sB[Ww], qA[Rr], qB[Ww];
    __shared__ float aw[Ww], br[Rr];
    int L = s_l[j];

    // ---- P0: zero att arrays; contiguous G-tile load (all 128 lanes) ----
    {
        uint* za = (uint*)attA;
        uint* zb = (uint*)attB;
#pragma unroll
        for (int k = 0; k < 14; ++k) {
            int idx = t + k * 128;
            if (idx < 48 * PAD / 2) { za[idx] = 0; zb[idx] = 0; }
        }
        const u16* gt = Gt + (size_t)(i * Bn + j) * TSZ;
        for (int c = t; c < 180; c += 128) {   // 180 chunks of 8 u16
            int r = c / 5, q = c - (c / 5) * 5;
            uint4 v = *(const uint4*)(gt + c * 8);
            *(uint2*)&glb[r * 44 + q * 8] = make_uint2(v.x, v.y);
            *(uint2*)&glb[r * 44 + q * 8 + 4] = make_uint2(v.z, v.w);
        }
    }
    float iid = 0.f, ssd = 0.f;
    if (wid == 0 && lane < Rr) iid = IId[i * Rr + lane];
    if (wid == 1 && lane < Ww) ssd = SSd[j * Ww + lane];
    __syncthreads();

    // ---- P1: norms ----
    if (wid == 0 && lane < Rr) {
        float sum = 0.f;
#pragma unroll 8
        for (int w = 0; w < Ww; ++w) {
            float x = bf2f(glb[lane * 44 + w]);
            x = x < 0.f ? 0.1f * x : x;
            sum += x * x;
        }
        invB[lane] = 9.f / (sqrtf(sum) + EPSf);
    }
    if (wid == 1 && lane < Ww) {
        float sum = 0.f;
#pragma unroll 6
        for (int r = 0; r < Rr; ++r) {
            float x = bf2f(glb[r * 44 + lane]);
            x = x < 0.f ? 0.1f * x : x;
            sum += x * x;
        }
        invA[lane] = 6.f / (sqrtf(sum) + EPSf);
    }
    __syncthreads();

    // ---- P2: softmax (no-max; args bounded) + fused dot ----
    float dot = 0.f, myinv = 0.f;
    if (wid == 0 && lane < Rr) {
        float ssum = 0.f;
#pragma unroll 8
        for (int w = 0; w < Ww; ++w) {
            float e = 0.f;
            if (w < L) {
                float gx = bf2f(glb[lane * 44 + w]);
                float x = gx < 0.f ? 0.1f * gx : gx;
                e = __expf(x * invA[w]);
                dot += e * gx;
            }
            attA[lane * PAD + w] = f2bf(e);
            ssum += e;
        }
        myinv = 1.f / ssum;
        dot *= myinv;
        sA[lane] = myinv;
    }
    if (wid == 1 && lane < Ww) {
        float ssum = 0.f;
#pragma unroll 6
        for (int r = 0; r < Rr; ++r) {
            float gx = bf2f(glb[r * 44 + lane]);
            float x = gx < 0.f ? 0.1f * gx : gx;
            float e = __expf(x * invB[r]);
            dot += e * gx;
            attB[lane * PAD + r] = f2bf(e);
            ssum += e;
        }
        myinv = 1.f / ssum;
        dot *= myinv;
        sB[lane] = myinv;
    }
    __syncthreads();

    // ---- P3: MFMA quadratic forms ----
    if (wid == 0)
        quad_mfma(attA, SSb + (size_t)j * 48 * SBP, qA, Rr, lane);
    else
        quad_mfma(attB, IIb + (size_t)i * 48 * SBP, qB, Ww, lane);

    // ---- P4: sims + LSE ----
    if (wid == 0) {
        float e1 = 0.f;
        if (lane < Rr) {
            float q = qA[lane] * myinv * myinv;
            float s1 = dot / fmaxf(sqrtf(iid) * sqrtf(fmaxf(q, 0.f)), EPSf);
            e1 = __expf(6.f * s1);
        }
#pragma unroll
        for (int off = 1; off < 64; off <<= 1) e1 += __shfl_xor(e1, off);
        if (lane == 0) score1[i * Bn + j] = __logf(e1) * (1.f / 6.f);
    } else {
        float e2 = 0.f;
        if (lane < Ww) {
            float q = qB[lane] * myinv * myinv;
            float s2 = dot / fmaxf(sqrtf(ssd) * sqrtf(fmaxf(q, 0.f)), EPSf);
            e2 = (lane < L) ? __expf(6.f * s2) : 0.f;
        }
#pragma unroll
        for (int off = 1; off < 64; off <<= 1) e2 += __shfl_xor(e2, off);
        if (lane == 0) score2[i * Bn + j] = __logf(e2) * (1.f / 6.f);
    }

    // ---- diag blocks: coefficients + vectorized output streaming ----
    if (i == j) {
        __syncthreads();
        if (wid == 1 && lane < Ww) {
            float sum = 0.f;
#pragma unroll 6
            for (int r = 0; r < Rr; ++r) sum += bf2f(attA[r * PAD + lane]) * sA[r];
            aw[lane] = sum * (1.f / (float)Rr);
        }
        if (wid == 0 && lane < Rr) {
            float sum = 0.f;
            for (int w = 0; w < L; ++w) sum += bf2f(attB[w * PAD + lane]) * sB[w];
            br[lane] = sum / (float)L;
        }
        __syncthreads();
        int d0 = t * 8;
        const u16* BbI = Bb + (size_t)i * Ww * Dd + d0;
        const u16* AbI = Ab + (size_t)i * Rr * Dd + d0;
        float a1[8], a2[8];
#pragma unroll
        for (int k = 0; k < 8; ++k) { a1[k] = 0.f; a2[k] = 0.f; }
        for (int w = 0; w < L; ++w) {
            bf16x8 v = *(const bf16x8*)(BbI + (size_t)w * Dd);
            float c = aw[w];
#pragma unroll
            for (int k = 0; k < 8; ++k) a1[k] += c * bf2f((u16)v[k]);
        }
#pragma unroll 6
        for (int r = 0; r < Rr; ++r) {
            bf16x8 v = *(const bf16x8*)(AbI + (size_t)r * Dd);
            float c = br[r];
#pragma unroll
            for (int k = 0; k < 8; ++k) a2[k] += c * bf2f((u16)v[k]);
        }
        float* o1 = out + 1 + (size_t)i * Dd + d0;
        float* o2 = out + 1 + (size_t)Bn * Dd + (size_t)i * Dd + d0;
#pragma unroll
        for (int k = 0; k < 8; ++k) { o1[k] = a1[k]; o2[k] = a2[k]; }
    }
}

// ================= hinge loss =================
__global__ void loss_kernel(const float* __restrict__ s1,
                            const float* __restrict__ s2,
                            float* __restrict__ out) {
    int t = threadIdx.x;
    __shared__ float sc[Bn][Bn + 1];
    for (int idx = t; idx < Bn * Bn; idx += 64)
        sc[idx >> 6][idx & 63] = 0.5f * (s1[idx] + s2[idx]);
    __syncthreads();
    float dt = sc[t][t];
    float rowmax = 0.f, colmax = 0.f;
    for (int k = 0; k < Bn; ++k) {
        if (k != t) {
            float cs = 0.2f + sc[t][k] - dt;
            if (cs > rowmax) rowmax = cs;
            float ci = 0.2f + sc[k][t] - dt;
            if (ci > colmax) colmax = ci;
        }
    }
    float v = rowmax + colmax;
    for (int off = 32; off; off >>= 1) v += __shfl_down(v, off);
    if (t == 0) out[0] = v;
}

extern "C" void kernel_launch(void* const* d_in, const int* in_sizes, int n_in,
                              void* d_out, int out_size, void* d_ws, size_t ws_size,
                              hipStream_t stream) {
    const float* im = (const float*)d_in[0];
    const float* s = (const float*)d_in[1];
    const int* s_l = (const int*)d_in[2];
    float* out = (float*)d_out;

    u16* Ab = (u16*)d_ws;                         // GM*Dd
    u16* Bb = Ab + (size_t)GM * Dd;               // GN*Dd
    u16* Gt = Bb + (size_t)GN * Dd;               // GM*GN (tiled: 4096 x 1440)
    u16* SSb = Gt + (size_t)GM * GN;              // 64*48*64
    u16* IIb = SSb + (size_t)Bn * 48 * SBP;       // 64*48*64
    float* SSd = (float*)(IIb + (size_t)Bn * 48 * SBP);
    float* IId = SSd + (size_t)Bn * Ww;
    float* score1 = IId + (size_t)Bn * Rr;
    float* score2 = score1 + Bn * Bn;

    convert_kernel<<<NCONV, 256, 0, stream>>>(im, s, s_l, Ab, Bb);

    gemm_gram_kernel<<<360 + 2 * Bn, 256, 0, stream>>>(Ab, Bb, Gt, SSb, IIb, SSd, IId);

    dim3 pgrid(Bn, Bn);
    pair_kernel<<<pgrid, 128, 0, stream>>>(Gt, SSb, IIb, SSd, IId, Ab, Bb, s_l,
                                           score1, score2, out);

    loss_kernel<<<1, 64, 0, stream>>>(score1, score2, out);
}